// Round 4
// baseline (129.306 us; speedup 1.0000x reference)
//
#include <hip/hip_runtime.h>
#include <math.h>

#define S_PNTS 8
#define NUM_POINTS 2
#define NB 8
#define NQ 500
#define NC 256
#define S_SCALE 0.077f
#define QPB 8                 // queries per block
#define ROWS (QPB * S_PNTS)   // 64 M-rows per block
#define APAD 264              // LDS leading dim bf16: 528 B -> 16B-aligned rows, 2-way bank alias only (free)
#define BLK 512               // 8 waves: wave = (M-half, N-slice)

typedef __bf16 bf16x8 __attribute__((ext_vector_type(8)));
typedef __bf16 bf16x4 __attribute__((ext_vector_type(4)));
typedef float  f32x4  __attribute__((ext_vector_type(4)));

__device__ __forceinline__ float fast_tanh(float x) {
    float xc = fminf(fmaxf(x, -14.0f), 14.0f);
    float t  = __builtin_amdgcn_exp2f(xc * 2.88539008178f);
    return 1.0f - 2.0f * __builtin_amdgcn_rcpf(t + 1.0f);
}

// ---- prep: W1 (256x256 fp32, [k][n]) -> W1t (256x256 bf16, [n][k]) in ws ----
__global__ __launch_bounds__(256) void prep_w1(const float* __restrict__ W1,
                                               __bf16* __restrict__ W1t) {
    __shared__ float tile[16][17];
    const int n0 = blockIdx.x * 16, k0 = blockIdx.y * 16;
    const int tx = threadIdx.x & 15, ty = threadIdx.x >> 4;
    tile[ty][tx] = W1[(k0 + ty) * NC + n0 + tx];
    __syncthreads();
    W1t[(n0 + ty) * NC + k0 + tx] = (__bf16)tile[tx][ty];
}

__global__ __launch_bounds__(BLK) void decoder_kernel(
    const float* __restrict__ ref_polys,   // (B, Q, 8)
    const int*   __restrict__ ref_levels,  // (B, Q)
    const float* __restrict__ memory,      // (B, 8500, 256)
    const __bf16* __restrict__ W1t,        // (256, 256) [n][k] bf16 (ws)
    const float* __restrict__ b1,          // (256,)
    const float* __restrict__ W2,          // (256, 4)
    const float* __restrict__ b2,          // (4,)
    float*       __restrict__ out)         // (B, Q, 16, 2)
{
    const int tid = threadIdx.x;

    __shared__ __bf16 emb_lds[ROWS * APAD];        // 33.8 KB; A-tile, then reused for h
    __shared__ float  w2t[4 * 260];                // W2 transposed [j][k]
    __shared__ float  b1_lds[NC];
    __shared__ int4   p_idx[ROWS];
    __shared__ float4 p_w[ROWS];
    __shared__ float2 spts_lds[ROWS];

    // ---- phase 1: per-row sampling params (one wave) ----
    if (tid < ROWS) {
        const int r = tid, s = r & 7;
        const int qg = blockIdx.x * QPB + (r >> 3);
        const int b  = qg / NQ;
        const int lvl = ref_levels[qg];
        const int W  = 80 >> lvl;                                    // 80,40,20,10
        const int st = (lvl >= 1) * 6400 + (lvl >= 2) * 1600 + (lvl >= 3) * 400;
        const float* rp = ref_polys + (size_t)qg * 8;
        float lam = (float)s * (1.0f / 7.0f);
        float sx = 2.0f * ((((rp[0] * lam + rp[1]) * lam + rp[2]) * lam + rp[3]) - 0.5f);
        float sy = 2.0f * ((((rp[4] * lam + rp[5]) * lam + rp[6]) * lam + rp[7]) - 0.5f);
        spts_lds[r] = make_float2(sx, sy);
        float gx = (sx + 1.0f) * 0.5f * (float)W - 0.5f;
        float gy = (sy + 1.0f) * 0.5f * (float)W - 0.5f;
        float x0f = floorf(gx), y0f = floorf(gy);
        int   x0 = (int)x0f,    y0 = (int)y0f;
        float wx1 = gx - x0f, wx0 = 1.0f - wx1;
        float wy1 = gy - y0f, wy0 = 1.0f - wy1;
        float xv0 = (x0 >= 0 && x0 < W) ? 1.0f : 0.0f;
        float xv1 = (x0 + 1 >= 0 && x0 + 1 < W) ? 1.0f : 0.0f;
        float yv0 = (y0 >= 0 && y0 < W) ? 1.0f : 0.0f;
        float yv1 = (y0 + 1 >= 0 && y0 + 1 < W) ? 1.0f : 0.0f;
        int xc0 = min(max(x0, 0), W - 1),     xc1 = min(max(x0 + 1, 0), W - 1);
        int yc0 = min(max(y0, 0), W - 1),     yc1 = min(max(y0 + 1, 0), W - 1);
        int base = b * 8500 + st;
        p_idx[r] = make_int4(base + yc0 * W + xc0, base + yc0 * W + xc1,
                             base + yc1 * W + xc0, base + yc1 * W + xc1);
        p_w[r] = make_float4(wy0 * wx0 * yv0 * xv0, wy0 * wx1 * yv0 * xv1,
                             wy1 * wx0 * yv1 * xv0, wy1 * wx1 * yv1 * xv1);
    }
    // ---- stage W2 (transposed fp32) + b1 into LDS ----
    #pragma unroll
    for (int i = tid; i < NC * 4; i += BLK) {
        int k = i >> 2, j = i & 3;
        w2t[j * 260 + k] = W2[i];
    }
    if (tid < NC) b1_lds[tid] = b1[tid];
    __syncthreads();

    // ---- phase 2: bilinear gather -> emb_lds bf16 (A-tile), float4 loads ----
    {
        const int c4  = tid & 63;       // float4 channel index
        const int rg0 = tid >> 6;       // 8 rows per pass
        const float4* m4 = (const float4*)memory;
        #pragma unroll
        for (int i = 0; i < 8; ++i) {
            int r = i * 8 + rg0;
            int4   id = p_idx[r];
            float4 wv = p_w[r];
            float4 v00 = m4[(size_t)id.x * 64 + c4];
            float4 v01 = m4[(size_t)id.y * 64 + c4];
            float4 v10 = m4[(size_t)id.z * 64 + c4];
            float4 v11 = m4[(size_t)id.w * 64 + c4];
            bf16x4 e;
            e[0] = (__bf16)(wv.x * v00.x + wv.y * v01.x + wv.z * v10.x + wv.w * v11.x);
            e[1] = (__bf16)(wv.x * v00.y + wv.y * v01.y + wv.z * v10.y + wv.w * v11.y);
            e[2] = (__bf16)(wv.x * v00.z + wv.y * v01.z + wv.z * v10.z + wv.w * v11.z);
            e[3] = (__bf16)(wv.x * v00.w + wv.y * v01.w + wv.z * v10.w + wv.w * v11.w);
            *(bf16x4*)&emb_lds[r * APAD + c4 * 4] = e;
        }
    }
    __syncthreads();

    // ---- phase 3: layer-1 MFMA. wave = (M-half mh, N-slice ns); 2 M-tiles x 4 N-tiles ----
    const int w    = tid >> 6;
    const int ns   = w & 3;        // N-slice: cols [ns*64, ns*64+64)
    const int mh   = w >> 2;       // M-half:  rows [mh*32, mh*32+32)
    const int l    = tid & 63;
    const int lrow = l & 15;
    const int quad = l >> 4;

    f32x4 acc[2][4] = {};
    #pragma unroll
    for (int ks = 0; ks < 8; ++ks) {
        bf16x8 a[2];
        #pragma unroll
        for (int mt = 0; mt < 2; ++mt)
            a[mt] = *(const bf16x8*)&emb_lds[(mh * 32 + mt * 16 + lrow) * APAD + ks * 32 + quad * 8];
        #pragma unroll
        for (int nt = 0; nt < 4; ++nt) {
            const int n = ns * 64 + nt * 16 + lrow;
            bf16x8 bf = *(const bf16x8*)&W1t[n * NC + ks * 32 + quad * 8];
            #pragma unroll
            for (int mt = 0; mt < 2; ++mt)
                acc[mt][nt] = __builtin_amdgcn_mfma_f32_16x16x32_bf16(a[mt], bf, acc[mt][nt], 0, 0, 0);
        }
    }
    __syncthreads();   // all waves done reading emb before overwrite with h

    // ---- phase 4: h = fast_tanh(acc + b1) -> bf16 back into emb_lds ----
    #pragma unroll
    for (int mt = 0; mt < 2; ++mt) {
        #pragma unroll
        for (int nt = 0; nt < 4; ++nt) {
            const int n = ns * 64 + nt * 16 + lrow;
            const float bias = b1_lds[n];
            #pragma unroll
            for (int rg = 0; rg < 4; ++rg) {
                const int row = mh * 32 + mt * 16 + quad * 4 + rg;
                emb_lds[row * APAD + n] = (__bf16)fast_tanh(acc[mt][nt][rg] + bias);
            }
        }
    }
    __syncthreads();

    // ---- phase 5: layer 2 + epilogue. thread = (row r, output j, k-half) ----
    {
        const int r    = tid >> 3;       // 0..63
        const int j    = (tid >> 1) & 3;
        const int half = tid & 1;
        float sum = 0.0f;
        const int kbase = half * 128;
        #pragma unroll
        for (int i = 0; i < 16; ++i) {
            const int k = kbase + i * 8;
            bf16x8 hv = *(const bf16x8*)&emb_lds[r * APAD + k];
            f32x4 wa = *(const f32x4*)&w2t[j * 260 + k];
            f32x4 wb = *(const f32x4*)&w2t[j * 260 + k + 4];
            sum += (float)hv[0] * wa[0] + (float)hv[1] * wa[1]
                 + (float)hv[2] * wa[2] + (float)hv[3] * wa[3]
                 + (float)hv[4] * wb[0] + (float)hv[5] * wb[1]
                 + (float)hv[6] * wb[2] + (float)hv[7] * wb[3];
        }
        sum += __shfl_xor(sum, 1);       // combine the two k-halves
        if (half == 0) {
            float o = S_SCALE * fast_tanh(sum + b2[j]);
            const int s  = r & 7;
            const int qg = blockIdx.x * QPB + (r >> 3);
            const int coord = j & 1;
            float sp = (coord == 0) ? spts_lds[r].x : spts_lds[r].y;
            out[(size_t)qg * 32 + s * 4 + j] = o + sp;
        }
    }
}

extern "C" void kernel_launch(void* const* d_in, const int* in_sizes, int n_in,
                              void* d_out, int out_size, void* d_ws, size_t ws_size,
                              hipStream_t stream) {
    const float* ref_polys  = (const float*)d_in[0];
    const int*   ref_levels = (const int*)d_in[1];
    const float* memory     = (const float*)d_in[2];
    const float* W1         = (const float*)d_in[3];
    const float* b1         = (const float*)d_in[4];
    const float* W2         = (const float*)d_in[5];
    const float* b2         = (const float*)d_in[6];
    float* out = (float*)d_out;

    __bf16* W1t = (__bf16*)d_ws;   // 128 KB of ws

    prep_w1<<<dim3(16, 16), dim3(256), 0, stream>>>(W1, W1t);
    decoder_kernel<<<dim3(NB * NQ / QPB), dim3(BLK), 0, stream>>>(
        ref_polys, ref_levels, memory, W1t, b1, W2, b2, out);
}

// Round 5
// 124.866 us; speedup vs baseline: 1.0356x; 1.0356x over previous
//
#include <hip/hip_runtime.h>
#include <math.h>

#define S_PNTS 8
#define NUM_POINTS 2
#define NB 8
#define NQ 500
#define NC 256
#define S_SCALE 0.077f
#define QPB 8                 // queries per block
#define ROWS (QPB * S_PNTS)   // 64 M-rows per block
#define APAD 264              // LDS leading dim bf16: 528 B -> 16B-aligned rows, 2-way bank alias only (free)

typedef __bf16 bf16x8 __attribute__((ext_vector_type(8)));
typedef __bf16 bf16x4 __attribute__((ext_vector_type(4)));
typedef float  f32x4  __attribute__((ext_vector_type(4)));

__device__ __forceinline__ float fast_tanh(float x) {
    float xc = fminf(fmaxf(x, -14.0f), 14.0f);
    float t  = __builtin_amdgcn_exp2f(xc * 2.88539008178f);
    return 1.0f - 2.0f * __builtin_amdgcn_rcpf(t + 1.0f);
}

// ---- prep: W1 (256x256 fp32, [k][n]) -> W1t (256x256 bf16, [n][k]) in ws ----
__global__ __launch_bounds__(256) void prep_w1(const float* __restrict__ W1,
                                               __bf16* __restrict__ W1t) {
    __shared__ float tile[16][17];
    const int n0 = blockIdx.x * 16, k0 = blockIdx.y * 16;
    const int tx = threadIdx.x & 15, ty = threadIdx.x >> 4;
    tile[ty][tx] = W1[(k0 + ty) * NC + n0 + tx];
    __syncthreads();
    W1t[(n0 + ty) * NC + k0 + tx] = (__bf16)tile[tx][ty];
}

// 256 threads, 4 waves; wave w owns output cols [w*64, w*64+64).
// __launch_bounds__(256,2): cap VGPR <= 256 so 2 waves/SIMD (2 blocks/CU) hold.
__global__ __launch_bounds__(256, 2) void decoder_kernel(
    const float* __restrict__ ref_polys,   // (B, Q, 8)
    const int*   __restrict__ ref_levels,  // (B, Q)
    const float* __restrict__ memory,      // (B, 8500, 256)
    const __bf16* __restrict__ W1t,        // (256, 256) [n][k] bf16 (ws)
    const float* __restrict__ b1,          // (256,)
    const float* __restrict__ W2,          // (256, 4)
    const float* __restrict__ b2,          // (4,)
    float*       __restrict__ out)         // (B, Q, 16, 2)
{
    const int tid  = threadIdx.x;
    const int w    = tid >> 6;
    const int l    = tid & 63;
    const int lrow = l & 15;
    const int quad = l >> 4;

    __shared__ __bf16 emb_lds[ROWS * APAD];        // 33.8 KB A-tile
    __shared__ __bf16 h_lds[ROWS * APAD];          // 33.8 KB h (separate -> one fewer barrier)
    __shared__ float  w2t[4 * 260];                // W2 transposed [j][k]
    __shared__ float  b1_lds[NC];
    __shared__ int4   p_idx[ROWS];
    __shared__ float4 p_w[ROWS];
    __shared__ float2 spts_lds[ROWS];

    // ---- phase 0: prefetch ALL B-fragments for this wave (independent of gather).
    // 32 frags x 16 B = 128 VGPRs; L2 latency hides under phases 1-2.
    bf16x8 bfrag[8][4];
    #pragma unroll
    for (int ks = 0; ks < 8; ++ks)
        #pragma unroll
        for (int nt = 0; nt < 4; ++nt)
            bfrag[ks][nt] = *(const bf16x8*)&W1t[(w * 64 + nt * 16 + lrow) * NC + ks * 32 + quad * 8];

    // ---- phase 1: per-row sampling params (one wave) ----
    if (tid < ROWS) {
        const int r = tid, s = r & 7;
        const int qg = blockIdx.x * QPB + (r >> 3);
        const int b  = qg / NQ;
        const int lvl = ref_levels[qg];
        const int W  = 80 >> lvl;                                    // 80,40,20,10
        const int st = (lvl >= 1) * 6400 + (lvl >= 2) * 1600 + (lvl >= 3) * 400;
        const float* rp = ref_polys + (size_t)qg * 8;
        float lam = (float)s * (1.0f / 7.0f);
        float sx = 2.0f * ((((rp[0] * lam + rp[1]) * lam + rp[2]) * lam + rp[3]) - 0.5f);
        float sy = 2.0f * ((((rp[4] * lam + rp[5]) * lam + rp[6]) * lam + rp[7]) - 0.5f);
        spts_lds[r] = make_float2(sx, sy);
        float gx = (sx + 1.0f) * 0.5f * (float)W - 0.5f;
        float gy = (sy + 1.0f) * 0.5f * (float)W - 0.5f;
        float x0f = floorf(gx), y0f = floorf(gy);
        int   x0 = (int)x0f,    y0 = (int)y0f;
        float wx1 = gx - x0f, wx0 = 1.0f - wx1;
        float wy1 = gy - y0f, wy0 = 1.0f - wy1;
        float xv0 = (x0 >= 0 && x0 < W) ? 1.0f : 0.0f;
        float xv1 = (x0 + 1 >= 0 && x0 + 1 < W) ? 1.0f : 0.0f;
        float yv0 = (y0 >= 0 && y0 < W) ? 1.0f : 0.0f;
        float yv1 = (y0 + 1 >= 0 && y0 + 1 < W) ? 1.0f : 0.0f;
        int xc0 = min(max(x0, 0), W - 1),     xc1 = min(max(x0 + 1, 0), W - 1);
        int yc0 = min(max(y0, 0), W - 1),     yc1 = min(max(y0 + 1, 0), W - 1);
        int base = b * 8500 + st;
        p_idx[r] = make_int4(base + yc0 * W + xc0, base + yc0 * W + xc1,
                             base + yc1 * W + xc0, base + yc1 * W + xc1);
        p_w[r] = make_float4(wy0 * wx0 * yv0 * xv0, wy0 * wx1 * yv0 * xv1,
                             wy1 * wx0 * yv1 * xv0, wy1 * wx1 * yv1 * xv1);
    }
    // ---- stage W2 (transposed fp32) + b1 into LDS ----
    #pragma unroll
    for (int i = tid; i < NC * 4; i += 256) {
        int k = i >> 2, j = i & 3;
        w2t[j * 260 + k] = W2[i];
    }
    b1_lds[tid] = b1[tid];
    __syncthreads();

    // ---- phase 2: bilinear gather -> emb_lds bf16, float4 loads ----
    {
        const int c4  = tid & 63;
        const int rg0 = tid >> 6;
        const float4* m4 = (const float4*)memory;
        #pragma unroll
        for (int i = 0; i < 16; ++i) {
            int r = i * 4 + rg0;
            int4   id = p_idx[r];
            float4 wv = p_w[r];
            float4 v00 = m4[(size_t)id.x * 64 + c4];
            float4 v01 = m4[(size_t)id.y * 64 + c4];
            float4 v10 = m4[(size_t)id.z * 64 + c4];
            float4 v11 = m4[(size_t)id.w * 64 + c4];
            bf16x4 e;
            e[0] = (__bf16)(wv.x * v00.x + wv.y * v01.x + wv.z * v10.x + wv.w * v11.x);
            e[1] = (__bf16)(wv.x * v00.y + wv.y * v01.y + wv.z * v10.y + wv.w * v11.y);
            e[2] = (__bf16)(wv.x * v00.z + wv.y * v01.z + wv.z * v10.z + wv.w * v11.z);
            e[3] = (__bf16)(wv.x * v00.w + wv.y * v01.w + wv.z * v10.w + wv.w * v11.w);
            *(bf16x4*)&emb_lds[r * APAD + c4 * 4] = e;
        }
    }
    __syncthreads();

    // ---- phase 3: layer-1 MFMA, zero global loads (B already in regs) ----
    f32x4 acc[4][4] = {};
    #pragma unroll
    for (int ks = 0; ks < 8; ++ks) {
        bf16x8 a[4];
        #pragma unroll
        for (int mt = 0; mt < 4; ++mt)
            a[mt] = *(const bf16x8*)&emb_lds[(mt * 16 + lrow) * APAD + ks * 32 + quad * 8];
        #pragma unroll
        for (int nt = 0; nt < 4; ++nt)
            #pragma unroll
            for (int mt = 0; mt < 4; ++mt)
                acc[mt][nt] = __builtin_amdgcn_mfma_f32_16x16x32_bf16(a[mt], bfrag[ks][nt], acc[mt][nt], 0, 0, 0);
    }

    // ---- phase 4: h = fast_tanh(acc + b1) -> h_lds (separate buffer, no pre-barrier) ----
    #pragma unroll
    for (int mt = 0; mt < 4; ++mt) {
        #pragma unroll
        for (int nt = 0; nt < 4; ++nt) {
            const int n = w * 64 + nt * 16 + lrow;
            const float bias = b1_lds[n];
            #pragma unroll
            for (int rg = 0; rg < 4; ++rg) {
                const int row = mt * 16 + quad * 4 + rg;
                h_lds[row * APAD + n] = (__bf16)fast_tanh(acc[mt][nt][rg] + bias);
            }
        }
    }
    __syncthreads();

    // ---- phase 5: layer 2 + epilogue. thread = (row r, output j), full-K dot ----
    {
        const int r = tid >> 2;        // 0..63
        const int j = tid & 3;
        float sum = b2[j];
        #pragma unroll
        for (int i = 0; i < 32; ++i) {
            const int k = i * 8;
            bf16x8 hv = *(const bf16x8*)&h_lds[r * APAD + k];
            f32x4 wa = *(const f32x4*)&w2t[j * 260 + k];
            f32x4 wb = *(const f32x4*)&w2t[j * 260 + k + 4];
            sum += (float)hv[0] * wa[0] + (float)hv[1] * wa[1]
                 + (float)hv[2] * wa[2] + (float)hv[3] * wa[3]
                 + (float)hv[4] * wb[0] + (float)hv[5] * wb[1]
                 + (float)hv[6] * wb[2] + (float)hv[7] * wb[3];
        }
        float o = S_SCALE * fast_tanh(sum);
        const int s  = r & 7;
        const int qg = blockIdx.x * QPB + (r >> 3);
        const int coord = j & 1;
        float sp = (coord == 0) ? spts_lds[r].x : spts_lds[r].y;
        out[(size_t)qg * 32 + s * 4 + j] = o + sp;
    }
}

extern "C" void kernel_launch(void* const* d_in, const int* in_sizes, int n_in,
                              void* d_out, int out_size, void* d_ws, size_t ws_size,
                              hipStream_t stream) {
    const float* ref_polys  = (const float*)d_in[0];
    const int*   ref_levels = (const int*)d_in[1];
    const float* memory     = (const float*)d_in[2];
    const float* W1         = (const float*)d_in[3];
    const float* b1         = (const float*)d_in[4];
    const float* W2         = (const float*)d_in[5];
    const float* b2         = (const float*)d_in[6];
    float* out = (float*)d_out;

    __bf16* W1t = (__bf16*)d_ws;   // 128 KB of ws

    prep_w1<<<dim3(16, 16), dim3(256), 0, stream>>>(W1, W1t);
    decoder_kernel<<<dim3(NB * NQ / QPB), dim3(256), 0, stream>>>(
        ref_polys, ref_levels, memory, W1t, b1, W2, b2, out);
}